// Round 10
// baseline (413.687 us; speedup 1.0000x reference)
//
#include <hip/hip_runtime.h>
#include <math.h>

#define CDIM 512
#define NDIM 4096
#define KDIM 64
#define BDIM 16
#define NSPLIT 8

typedef __attribute__((ext_vector_type(8))) _Float16 f16x8;
typedef __attribute__((ext_vector_type(4))) _Float16 f16x4;
typedef __attribute__((ext_vector_type(4))) float f32x4;

__device__ __forceinline__ void g2lds16(const void* g, void* l) {
  __builtin_amdgcn_global_load_lds(
      (const __attribute__((address_space(1))) int*)g,
      (__attribute__((address_space(3))) int*)l, 16, 0, 0);
}

__device__ __forceinline__ f16x8 ldsfrag(const short* base, int row, int kk,
                                         int lh) {
  int slot = (kk * 4 + lh) ^ (row & 7);
  return *reinterpret_cast<const f16x8*>(&base[row * 64 + slot * 8]);
}

// ---------------------------------------------------------------------------
// x [b][c][n] f32 -> xT [b][n][c] fp16.  grid (N/64, C/64, B)
// ---------------------------------------------------------------------------
__global__ __launch_bounds__(256) void k_cvtT16(const float* __restrict__ in,
                                                _Float16* __restrict__ outT) {
  __shared__ __align__(16) _Float16 T[64][80];
  const int t = threadIdx.x;
  const int n0 = blockIdx.x * 64, c0 = blockIdx.y * 64;
  const float* ib = in + (size_t)blockIdx.z * CDIM * NDIM;
  _Float16* ob = outT + (size_t)blockIdx.z * NDIM * CDIM;
#pragma unroll
  for (int i = 0; i < 4; ++i) {
    int idx = i * 256 + t;
    int cl = idx >> 4, f4 = idx & 15;
    float4 v = *reinterpret_cast<const float4*>(
        &ib[(size_t)(c0 + cl) * NDIM + n0 + f4 * 4]);
    T[f4 * 4 + 0][cl] = (_Float16)v.x;
    T[f4 * 4 + 1][cl] = (_Float16)v.y;
    T[f4 * 4 + 2][cl] = (_Float16)v.z;
    T[f4 * 4 + 3][cl] = (_Float16)v.w;
  }
  __syncthreads();
#pragma unroll
  for (int i = 0; i < 2; ++i) {
    int idx = i * 256 + t;
    int nl = idx >> 3, ch = idx & 7;
    uint4 u = *reinterpret_cast<const uint4*>(&T[nl][ch * 8]);
    *reinterpret_cast<uint4*>(&ob[(size_t)(n0 + nl) * CDIM + c0 + ch * 8]) = u;
  }
}

// ---------------------------------------------------------------------------
// weights f32 -> fp16
// ---------------------------------------------------------------------------
__global__ void k_cvt_w16(const float* __restrict__ w,
                          _Float16* __restrict__ wh) {
  int i = (blockIdx.x * 256 + threadIdx.x) * 4;
  float4 v = *reinterpret_cast<const float4*>(&w[i]);
  wh[i] = (_Float16)v.x; wh[i + 1] = (_Float16)v.y;
  wh[i + 2] = (_Float16)v.z; wh[i + 3] = (_Float16)v.w;
}

// ---------------------------------------------------------------------------
// conv1: xf = W1*x + b1, dual-layout output:
//   xfT[b][n][o] fp16 (scalar writes) and xf[b][o][n] fp16 (via LDS transpose)
// grid (N/128, C/128, B); 128x128 tile, BK=64, 4 waves.
// ---------------------------------------------------------------------------
__global__ __launch_bounds__(256) void k_conv1_16(
    const _Float16* __restrict__ xT, const _Float16* __restrict__ w1,
    const float* __restrict__ b1, _Float16* __restrict__ xfT,
    _Float16* __restrict__ xf) {
  __shared__ __align__(16) short smem[17408];  // At[8192] Bt[8192]; Ot overlays
  short* At = smem;
  short* Bt = smem + 8192;
  const int tid = threadIdx.x;
  const int l = tid & 63, w = tid >> 6;
  const int wm = w >> 1, wn = w & 1;
  const int lr = l & 15, lh = l >> 4;
  const int i0 = blockIdx.x * 128;  // n
  const int j0 = blockIdx.y * 128;  // o
  const int b = blockIdx.z;
  const short* Ag = (const short*)(xT + (size_t)b * NDIM * CDIM);
  const short* Bg = (const short*)w1;
  f32x4 acc[4][4] = {};
  for (int c0 = 0; c0 < CDIM; c0 += 64) {
#pragma unroll
    for (int i = 0; i < 4; ++i) {
      int slot = i * 256 + tid;
      int r = slot >> 3, s = slot & 7, sp = s ^ (r & 7);
      g2lds16(Ag + (size_t)(i0 + r) * CDIM + c0 + sp * 8, At + slot * 8);
    }
#pragma unroll
    for (int i = 0; i < 4; ++i) {
      int slot = i * 256 + tid;
      int r = slot >> 3, s = slot & 7, sp = s ^ (r & 7);
      g2lds16(Bg + (size_t)(j0 + r) * CDIM + c0 + sp * 8, Bt + slot * 8);
    }
    __syncthreads();
#pragma unroll
    for (int kk = 0; kk < 2; ++kk) {
      f16x8 af[4], bf[4];
#pragma unroll
      for (int m = 0; m < 4; ++m) af[m] = ldsfrag(At, wm * 64 + m * 16 + lr, kk, lh);
#pragma unroll
      for (int nf = 0; nf < 4; ++nf) bf[nf] = ldsfrag(Bt, wn * 64 + nf * 16 + lr, kk, lh);
#pragma unroll
      for (int m = 0; m < 4; ++m)
#pragma unroll
        for (int nf = 0; nf < 4; ++nf)
          acc[m][nf] = __builtin_amdgcn_mfma_f32_16x16x32_f16(af[m], bf[nf],
                                                              acc[m][nf], 0, 0, 0);
    }
    __syncthreads();
  }
  // Epilogue: xfT scalar writes + scatter into Ot[o][n] (pad 136)
  _Float16* Otf = (_Float16*)smem;
  _Float16* ob = xfT + (size_t)b * NDIM * CDIM;
#pragma unroll
  for (int m = 0; m < 4; ++m) {
#pragma unroll
    for (int nf = 0; nf < 4; ++nf) {
      int ol = wn * 64 + nf * 16 + lr;
      float bv = b1[j0 + ol];
#pragma unroll
      for (int r = 0; r < 4; ++r) {
        int nl = wm * 64 + m * 16 + lh * 4 + r;
        _Float16 hv = (_Float16)(acc[m][nf][r] + bv);
        ob[(size_t)(i0 + nl) * CDIM + j0 + ol] = hv;
        Otf[ol * 136 + nl] = hv;
      }
    }
  }
  __syncthreads();
  _Float16* xfb = xf + (size_t)b * CDIM * NDIM;
#pragma unroll
  for (int i = 0; i < 8; ++i) {
    int seg = i * 256 + tid;
    int row = seg >> 4, cs = seg & 15;
    f16x8 v = *reinterpret_cast<const f16x8*>(&Otf[row * 136 + cs * 8]);
    *reinterpret_cast<f16x8*>(&xfb[(size_t)(j0 + row) * NDIM + i0 + cs * 8]) = v;
  }
}

// ---------------------------------------------------------------------------
// conv2: y16[b][o][n] fp16 = sum_c w2[o][c] reconT[n][c]; fused BN partial
// stats.  grid (N/128, C/128, B) — n on x so blocks sharing a reconT tile
// land on the same XCD (ids differ by 32, 32%8==0).
// ---------------------------------------------------------------------------
__global__ __launch_bounds__(256) void k_conv2_16(
    const _Float16* __restrict__ w2, const _Float16* __restrict__ reconT,
    _Float16* __restrict__ y16, float* __restrict__ bnsum,
    float* __restrict__ bnsumsq) {
  __shared__ __align__(16) short At[128 * 64];
  __shared__ __align__(16) short Bt[128 * 64];
  __shared__ float bns[128], bnq[128];
  const int tid = threadIdx.x;
  const int l = tid & 63, w = tid >> 6;
  const int wm = w >> 1, wn = w & 1;
  const int lr = l & 15, lh = l >> 4;
  const int i0 = blockIdx.y * 128;  // o
  const int j0 = blockIdx.x * 128;  // n
  const int b = blockIdx.z;
  if (tid < 128) { bns[tid] = 0.f; bnq[tid] = 0.f; }
  const short* Ag = (const short*)w2;
  const short* Bg = (const short*)(reconT + (size_t)b * NDIM * CDIM);
  f32x4 acc[4][4] = {};
  for (int c0 = 0; c0 < CDIM; c0 += 64) {
#pragma unroll
    for (int i = 0; i < 4; ++i) {
      int slot = i * 256 + tid;
      int r = slot >> 3, s = slot & 7, sp = s ^ (r & 7);
      g2lds16(Ag + (size_t)(i0 + r) * CDIM + c0 + sp * 8, At + slot * 8);
    }
#pragma unroll
    for (int i = 0; i < 4; ++i) {
      int slot = i * 256 + tid;
      int r = slot >> 3, s = slot & 7, sp = s ^ (r & 7);
      g2lds16(Bg + (size_t)(j0 + r) * CDIM + c0 + sp * 8, Bt + slot * 8);
    }
    __syncthreads();
#pragma unroll
    for (int kk = 0; kk < 2; ++kk) {
      f16x8 af[4], bf[4];
#pragma unroll
      for (int m = 0; m < 4; ++m) af[m] = ldsfrag(At, wm * 64 + m * 16 + lr, kk, lh);
#pragma unroll
      for (int nf = 0; nf < 4; ++nf) bf[nf] = ldsfrag(Bt, wn * 64 + nf * 16 + lr, kk, lh);
#pragma unroll
      for (int m = 0; m < 4; ++m)
#pragma unroll
        for (int nf = 0; nf < 4; ++nf)
          acc[m][nf] = __builtin_amdgcn_mfma_f32_16x16x32_f16(af[m], bf[nf],
                                                              acc[m][nf], 0, 0, 0);
    }
    __syncthreads();
  }
  _Float16* yb = y16 + (size_t)b * CDIM * NDIM;
#pragma unroll
  for (int m = 0; m < 4; ++m) {
#pragma unroll
    for (int r = 0; r < 4; ++r) {
      int ol = wm * 64 + m * 16 + lh * 4 + r;
      float ps = 0.f, pq = 0.f;
#pragma unroll
      for (int nf = 0; nf < 4; ++nf) {
        float v = acc[m][nf][r];
        ps += v; pq += v * v;
        yb[(size_t)(i0 + ol) * NDIM + j0 + wn * 64 + nf * 16 + lr] = (_Float16)v;
      }
#pragma unroll
      for (int d = 1; d < 16; d <<= 1) {
        ps += __shfl_xor(ps, d);
        pq += __shfl_xor(pq, d);
      }
      if (lr == 0) { atomicAdd(&bns[ol], ps); atomicAdd(&bnq[ol], pq); }
    }
  }
  __syncthreads();
  if (tid < 128) {
    atomicAdd(&bnsum[i0 + tid], bns[tid]);
    atomicAdd(&bnsumsq[i0 + tid], bnq[tid]);
  }
}

// ---------------------------------------------------------------------------
// init muT[b][k][c] fp16 = mu[c][k]
// ---------------------------------------------------------------------------
__global__ void k_init_mu16(const float* __restrict__ mu,
                            _Float16* __restrict__ muT) {
  int idx = blockIdx.x * 256 + threadIdx.x;  // 524288
  int rem = idx & 32767;
  int k = rem >> 9, c = rem & 511;
  muT[idx] = (_Float16)mu[c * KDIM + k];
}

// ---------------------------------------------------------------------------
// S1 (fp16 MFMA): logits[n][k] = sum_c xfT[n][c] muT[k][c]; z=softmax_k;
// writes z[b][n][k] (only if writeZ), zT[b][k][n] fp16, colsum[b][k].
// grid (N/256, B). 256n x 64k tile; 4 waves own 64 n-rows each (32 MFMA/step).
// zs (256x72 halves) overlays At/Bt after the K-loop.
// ---------------------------------------------------------------------------
__global__ __launch_bounds__(256) void k_s1_16(const _Float16* __restrict__ xfT,
                                               const _Float16* __restrict__ muT,
                                               _Float16* __restrict__ z,
                                               _Float16* __restrict__ zT,
                                               float* __restrict__ colsum,
                                               int writeZ) {
  __shared__ __align__(16) short smem[20480];  // At[16384] Bt[4096]; zs overlays
  short* At = smem;
  short* Bt = smem + 16384;
  _Float16* zs = (_Float16*)smem;  // [256][72] after K-loop
  __shared__ float csum[4][64];
  const int tid = threadIdx.x;
  const int l = tid & 63, w = tid >> 6;
  const int lr = l & 15, lh = l >> 4;
  const int n0 = blockIdx.x * 256;
  const int b = blockIdx.y;
  const short* Ag = (const short*)(xfT + (size_t)b * NDIM * CDIM);
  const short* Bg = (const short*)(muT + (size_t)b * KDIM * CDIM);
  f32x4 acc[4][4] = {};  // [nf][kf]
  for (int c0 = 0; c0 < CDIM; c0 += 64) {
#pragma unroll
    for (int i = 0; i < 8; ++i) {
      int slot = i * 256 + tid;
      int r = slot >> 3, s = slot & 7, sp = s ^ (r & 7);
      g2lds16(Ag + (size_t)(n0 + r) * CDIM + c0 + sp * 8, At + slot * 8);
    }
#pragma unroll
    for (int i = 0; i < 2; ++i) {
      int slot = i * 256 + tid;
      int r = slot >> 3, s = slot & 7, sp = s ^ (r & 7);
      g2lds16(Bg + (size_t)r * CDIM + c0 + sp * 8, Bt + slot * 8);
    }
    __syncthreads();
#pragma unroll
    for (int kk = 0; kk < 2; ++kk) {
      f16x8 af[4], bf;
#pragma unroll
      for (int nf = 0; nf < 4; ++nf)
        af[nf] = ldsfrag(At, w * 64 + nf * 16 + lr, kk, lh);
#pragma unroll
      for (int kf = 0; kf < 4; ++kf) {
        bf = ldsfrag(Bt, kf * 16 + lr, kk, lh);
#pragma unroll
        for (int nf = 0; nf < 4; ++nf)
          acc[nf][kf] = __builtin_amdgcn_mfma_f32_16x16x32_f16(af[nf], bf,
                                                               acc[nf][kf], 0, 0, 0);
      }
    }
    __syncthreads();
  }
  // softmax over k (all waves past final barrier; At/Bt dead -> zs overlay ok)
#pragma unroll
  for (int nf = 0; nf < 4; ++nf) {
#pragma unroll
    for (int r = 0; r < 4; ++r) {
      float m = fmaxf(fmaxf(acc[nf][0][r], acc[nf][1][r]),
                      fmaxf(acc[nf][2][r], acc[nf][3][r]));
#pragma unroll
      for (int d = 8; d >= 1; d >>= 1) m = fmaxf(m, __shfl_xor(m, d));
      float e[4], s = 0.f;
#pragma unroll
      for (int kf = 0; kf < 4; ++kf) { e[kf] = __expf(acc[nf][kf][r] - m); s += e[kf]; }
#pragma unroll
      for (int d = 8; d >= 1; d >>= 1) s += __shfl_xor(s, d);
      float inv = 1.f / s;
      int row = w * 64 + nf * 16 + lh * 4 + r;
#pragma unroll
      for (int kf = 0; kf < 4; ++kf)
        zs[row * 72 + kf * 16 + lr] = (_Float16)(e[kf] * inv);
    }
  }
  __syncthreads();
  _Float16* zTb = zT + (size_t)b * KDIM * NDIM;
  if (writeZ) {
    _Float16* zb = z + (size_t)b * NDIM * KDIM;
#pragma unroll
    for (int i = 0; i < 8; ++i) {  // z[n][k]
      int idx = i * 256 + tid;
      int n = idx >> 3, ch = idx & 7;
      *reinterpret_cast<uint4*>(&zb[(size_t)(n0 + n) * KDIM + ch * 8]) =
          *reinterpret_cast<const uint4*>(&zs[n * 72 + ch * 8]);
    }
  }
#pragma unroll
  for (int i = 0; i < 8; ++i) {  // zT[k][n]
    int idx = i * 256 + tid;
    int k = idx >> 5, nch = idx & 31;
    f16x8 v;
#pragma unroll
    for (int j = 0; j < 8; ++j) v[j] = zs[(nch * 8 + j) * 72 + k];
    *reinterpret_cast<f16x8*>(&zTb[(size_t)k * NDIM + n0 + nch * 8]) = v;
  }
  {  // colsum: thread (q=tid>>6, k=tid&63) sums 64 rows
    int k = tid & 63, q = tid >> 6;
    float s = 0.f;
#pragma unroll
    for (int n = 0; n < 64; ++n) s += (float)zs[(q * 64 + n) * 72 + k];
    csum[q][k] = s;
  }
  __syncthreads();
  if (tid < 64)
    atomicAdd(&colsum[b * KDIM + tid],
              csum[0][tid] + csum[1][tid] + csum[2][tid] + csum[3][tid]);
}

// ---------------------------------------------------------------------------
// S2 (fp16 MFMA): mu_part[s][b][k][c] = sum_{n in split} zT[k][n] xf[c][n]
// grid (C/256, NSPLIT=8, B). 64k x 256c tile; 4 waves own 64 c-cols each.
// ---------------------------------------------------------------------------
__global__ __launch_bounds__(256) void k_s2_16(const _Float16* __restrict__ zT,
                                               const _Float16* __restrict__ xf,
                                               float* __restrict__ mupart) {
  __shared__ __align__(16) short At[64 * 64];
  __shared__ __align__(16) short Bt[256 * 64];
  const int tid = threadIdx.x;
  const int l = tid & 63, w = tid >> 6;
  const int lr = l & 15, lh = l >> 4;
  const int c0 = blockIdx.x * 256;
  const int split = blockIdx.y;
  const int b = blockIdx.z;
  const short* Ag = (const short*)(zT + (size_t)b * KDIM * NDIM);
  const short* Bg = (const short*)(xf + (size_t)b * CDIM * NDIM);
  f32x4 acc[4][4] = {};  // [kf][cf]
  for (int st = 0; st < NDIM / NSPLIT / 64; ++st) {
    const int nb = split * (NDIM / NSPLIT) + st * 64;
#pragma unroll
    for (int i = 0; i < 2; ++i) {
      int slot = i * 256 + tid;
      int r = slot >> 3, s = slot & 7, sp = s ^ (r & 7);
      g2lds16(Ag + (size_t)r * NDIM + nb + sp * 8, At + slot * 8);
    }
#pragma unroll
    for (int i = 0; i < 8; ++i) {
      int slot = i * 256 + tid;
      int r = slot >> 3, s = slot & 7, sp = s ^ (r & 7);
      g2lds16(Bg + (size_t)(c0 + r) * NDIM + nb + sp * 8, Bt + slot * 8);
    }
    __syncthreads();
#pragma unroll
    for (int kk = 0; kk < 2; ++kk) {
      f16x8 bf[4], af;
#pragma unroll
      for (int cf = 0; cf < 4; ++cf)
        bf[cf] = ldsfrag(Bt, w * 64 + cf * 16 + lr, kk, lh);
#pragma unroll
      for (int kf = 0; kf < 4; ++kf) {
        af = ldsfrag(At, kf * 16 + lr, kk, lh);
#pragma unroll
        for (int cf = 0; cf < 4; ++cf)
          acc[kf][cf] = __builtin_amdgcn_mfma_f32_16x16x32_f16(af, bf[cf],
                                                               acc[kf][cf], 0, 0, 0);
      }
    }
    __syncthreads();
  }
  float* mp = mupart + ((size_t)(split * BDIM + b) * KDIM) * CDIM;
#pragma unroll
  for (int kf = 0; kf < 4; ++kf) {
    int k = kf * 16 + lh * 4;
#pragma unroll
    for (int r = 0; r < 4; ++r)
#pragma unroll
      for (int cf = 0; cf < 4; ++cf)
        mp[(size_t)(k + r) * CDIM + c0 + w * 64 + cf * 16 + lr] = acc[kf][cf][r];
  }
}

// ---------------------------------------------------------------------------
// S2 reduce: v[c] = sum_s mu_part; t = v*scs[k]; out = t/(1e-6+|t|_2)
// Also zeroes colsum[b][k] for the next stage (replaces per-stage memset).
// ---------------------------------------------------------------------------
__global__ __launch_bounds__(256) void k_s2red(const float* __restrict__ mupart,
                                               float* __restrict__ colsum,
                                               _Float16* __restrict__ muT,
                                               _Float16* __restrict__ mu_ck) {
  __shared__ float red[4];
  const int tid = threadIdx.x;
  const int b = blockIdx.x >> 6, k = blockIdx.x & 63;
  const float csv = colsum[b * KDIM + k];  // read before the barrier
  float v0 = 0.f, v1 = 0.f;
#pragma unroll
  for (int s = 0; s < NSPLIT; ++s) {
    const float* mp = mupart + ((size_t)(s * BDIM + b) * KDIM + k) * CDIM;
    v0 += mp[tid];
    v1 += mp[tid + 256];
  }
  float ssq = v0 * v0 + v1 * v1;
#pragma unroll
  for (int d = 32; d >= 1; d >>= 1) ssq += __shfl_down(ssq, d);
  if ((tid & 63) == 0) red[tid >> 6] = ssq;
  __syncthreads();
  if (tid == 0) colsum[b * KDIM + k] = 0.f;  // all threads read csv already
  float tot = red[0] + red[1] + red[2] + red[3];
  float scs = 1.f / (1e-6f + csv);
  float inv = scs / (1e-6f + scs * sqrtf(tot));
  _Float16 o0 = (_Float16)(v0 * inv), o1 = (_Float16)(v1 * inv);
  muT[((size_t)b * KDIM + k) * CDIM + tid] = o0;
  muT[((size_t)b * KDIM + k) * CDIM + tid + 256] = o1;
  mu_ck[((size_t)b * CDIM + tid) * KDIM + k] = o0;
  mu_ck[((size_t)b * CDIM + tid + 256) * KDIM + k] = o1;
}

// ---------------------------------------------------------------------------
// recon (fp16 MFMA): reconT[n][c] = relu(sum_k z[n][k] mu_ck[c][k])
// grid (N/128, C/128, B)
// ---------------------------------------------------------------------------
__global__ __launch_bounds__(256) void k_recon16(const _Float16* __restrict__ z,
                                                 const _Float16* __restrict__ mu_ck,
                                                 _Float16* __restrict__ reconT) {
  __shared__ __align__(16) short Az[128 * 64];
  __shared__ __align__(16) short Bm[128 * 64];
  const int tid = threadIdx.x;
  const int l = tid & 63, w = tid >> 6;
  const int wm = w >> 1, wn = w & 1;
  const int lr = l & 15, lh = l >> 4;
  const int n0 = blockIdx.x * 128;
  const int c0 = blockIdx.y * 128;
  const int b = blockIdx.z;
  const short* Ag = (const short*)(z + (size_t)b * NDIM * KDIM);
  const short* Bg = (const short*)(mu_ck + (size_t)b * CDIM * KDIM);
#pragma unroll
  for (int i = 0; i < 4; ++i) {
    int slot = i * 256 + tid;
    int r = slot >> 3, s = slot & 7, sp = s ^ (r & 7);
    g2lds16(Ag + (size_t)(n0 + r) * KDIM + sp * 8, Az + slot * 8);
  }
#pragma unroll
  for (int i = 0; i < 4; ++i) {
    int slot = i * 256 + tid;
    int r = slot >> 3, s = slot & 7, sp = s ^ (r & 7);
    g2lds16(Bg + (size_t)(c0 + r) * KDIM + sp * 8, Bm + slot * 8);
  }
  __syncthreads();
  f32x4 acc[4][4] = {};
#pragma unroll
  for (int kk = 0; kk < 2; ++kk) {
    f16x8 af[4], bf[4];
#pragma unroll
    for (int m = 0; m < 4; ++m) af[m] = ldsfrag(Az, wm * 64 + m * 16 + lr, kk, lh);
#pragma unroll
    for (int nf = 0; nf < 4; ++nf) bf[nf] = ldsfrag(Bm, wn * 64 + nf * 16 + lr, kk, lh);
#pragma unroll
    for (int m = 0; m < 4; ++m)
#pragma unroll
      for (int nf = 0; nf < 4; ++nf)
        acc[m][nf] = __builtin_amdgcn_mfma_f32_16x16x32_f16(af[m], bf[nf],
                                                            acc[m][nf], 0, 0, 0);
  }
  _Float16* ob = reconT + (size_t)b * NDIM * CDIM;
#pragma unroll
  for (int m = 0; m < 4; ++m) {
#pragma unroll
    for (int r = 0; r < 4; ++r) {
      int n = n0 + wm * 64 + m * 16 + lh * 4 + r;
#pragma unroll
      for (int nf = 0; nf < 4; ++nf) {
        int c = c0 + wn * 64 + nf * 16 + lr;
        ob[(size_t)n * CDIM + c] = (_Float16)fmaxf(acc[m][nf][r], 0.f);
      }
    }
  }
}

// ---------------------------------------------------------------------------
// final: out = relu((y-mean)*rsqrt(var+eps)*gamma + beta + x), y fp16
// ---------------------------------------------------------------------------
__global__ void k_final(float* __restrict__ out, const _Float16* __restrict__ y16,
                        const float* __restrict__ x,
                        const float* __restrict__ bnsum,
                        const float* __restrict__ bnsumsq,
                        const float* __restrict__ gamma,
                        const float* __restrict__ beta) {
  const float invM = 1.f / (BDIM * (float)NDIM);
  const size_t total4 = (size_t)BDIM * CDIM * NDIM / 4;
  for (size_t i4 = (size_t)blockIdx.x * 256 + threadIdx.x; i4 < total4;
       i4 += (size_t)gridDim.x * 256) {
    int c = (int)((i4 >> 10) & (CDIM - 1));
    float mean = bnsum[c] * invM;
    float var = bnsumsq[c] * invM - mean * mean;
    float sc = rsqrtf(var + 1e-5f) * gamma[c];
    float sh = beta[c] - mean * sc;
    f16x4 yv = *reinterpret_cast<const f16x4*>(&y16[i4 * 4]);
    float4 xv = reinterpret_cast<const float4*>(x)[i4];
    float4 o;
    o.x = fmaxf(fmaf((float)yv[0], sc, sh) + xv.x, 0.f);
    o.y = fmaxf(fmaf((float)yv[1], sc, sh) + xv.y, 0.f);
    o.z = fmaxf(fmaf((float)yv[2], sc, sh) + xv.z, 0.f);
    o.w = fmaxf(fmaf((float)yv[3], sc, sh) + xv.w, 0.f);
    reinterpret_cast<float4*>(out)[i4] = o;
  }
}

// ---------------------------------------------------------------------------
extern "C" void kernel_launch(void* const* d_in, const int* in_sizes, int n_in,
                              void* d_out, int out_size, void* d_ws,
                              size_t ws_size, hipStream_t stream) {
  const float* x = (const float*)d_in[0];
  const float* mu = (const float*)d_in[1];
  const float* w1 = (const float*)d_in[2];
  const float* b1 = (const float*)d_in[3];
  const float* w2 = (const float*)d_in[4];
  const float* gamma = (const float*)d_in[5];
  const float* beta = (const float*)d_in[6];
  float* out = (float*)d_out;

  // xf dual copies live in d_out until k_final overwrites it.
  _Float16* xfT = (_Float16*)d_out;              // [B][N][C]
  _Float16* xf = (_Float16*)d_out + 33554432;    // [B][C][N]

  _Float16* wsH = (_Float16*)d_ws;
  _Float16* xT = wsH;                            // [B][N][C] (reused as reconT)
  _Float16* reconT = wsH;
  _Float16* z = wsH + 33554432;                  // [B][N][K]
  _Float16* zT = z + 4194304;                    // [B][K][N]
  _Float16* muT = zT + 4194304;                  // [B][K][C]
  _Float16* mu_ck = muT + 524288;                // [B][C][K]
  _Float16* w1h = mu_ck + 524288;                // [C][C]
  _Float16* w2h = w1h + 262144;
  float* wsF = (float*)(w2h + 262144);
  float* mupart = wsF;                           // [S=8][B][K][C] f32
  float* colsum = mupart + 4194304;              // [B][K]
  float* bnsum = colsum + 1024;                  // [C]
  float* bnsumsq = bnsum + 512;                  // [C]
  _Float16* y16 = (_Float16*)(bnsumsq + 512);    // [B][C][N] fp16

  k_cvtT16<<<dim3(NDIM / 64, CDIM / 64, BDIM), 256, 0, stream>>>(x, xT);
  k_cvt_w16<<<CDIM * CDIM / 1024, 256, 0, stream>>>(w1, w1h);
  k_cvt_w16<<<CDIM * CDIM / 1024, 256, 0, stream>>>(w2, w2h);

  k_conv1_16<<<dim3(NDIM / 128, CDIM / 128, BDIM), 256, 0, stream>>>(
      xT, w1h, b1, xfT, xf);
  k_init_mu16<<<2048, 256, 0, stream>>>(mu, muT);

  // colsum zeroed once here; k_s2red re-zeroes it for subsequent stages.
  hipMemsetAsync(colsum, 0, 1024 * sizeof(float), stream);
  for (int s = 0; s < 3; ++s) {
    k_s1_16<<<dim3(NDIM / 256, BDIM), 256, 0, stream>>>(xfT, muT, z, zT, colsum,
                                                        s == 2 ? 1 : 0);
    k_s2_16<<<dim3(CDIM / 256, NSPLIT, BDIM), 256, 0, stream>>>(zT, xf, mupart);
    k_s2red<<<KDIM * BDIM, 256, 0, stream>>>(mupart, colsum, muT, mu_ck);
  }

  k_recon16<<<dim3(NDIM / 128, CDIM / 128, BDIM), 256, 0, stream>>>(z, mu_ck,
                                                                    reconT);
  hipMemsetAsync(bnsum, 0, 1024 * sizeof(float), stream);
  k_conv2_16<<<dim3(NDIM / 128, CDIM / 128, BDIM), 256, 0, stream>>>(
      w2h, reconT, y16, bnsum, bnsumsq);

  k_final<<<4096, 256, 0, stream>>>(out, y16, x, bnsum, bnsumsq, gamma, beta);
}

// Round 11
// 371.172 us; speedup vs baseline: 1.1145x; 1.1145x over previous
//
#include <hip/hip_runtime.h>
#include <math.h>

#define CDIM 512
#define NDIM 4096
#define KDIM 64
#define BDIM 16
#define NSPLIT 8

typedef __attribute__((ext_vector_type(8))) _Float16 f16x8;
typedef __attribute__((ext_vector_type(4))) _Float16 f16x4;
typedef __attribute__((ext_vector_type(4))) float f32x4;

__device__ __forceinline__ void g2lds16(const void* g, void* l) {
  __builtin_amdgcn_global_load_lds(
      (const __attribute__((address_space(1))) int*)g,
      (__attribute__((address_space(3))) int*)l, 16, 0, 0);
}

__device__ __forceinline__ f16x8 ldsfrag(const short* base, int row, int kk,
                                         int lh) {
  int slot = (kk * 4 + lh) ^ (row & 7);
  return *reinterpret_cast<const f16x8*>(&base[row * 64 + slot * 8]);
}

// ---------------------------------------------------------------------------
// x [b][c][n] f32 -> xT [b][n][c] fp16.  grid (N/64, C/64, B)
// ---------------------------------------------------------------------------
__global__ __launch_bounds__(256) void k_cvtT16(const float* __restrict__ in,
                                                _Float16* __restrict__ outT) {
  __shared__ __align__(16) _Float16 T[64][80];
  const int t = threadIdx.x;
  const int n0 = blockIdx.x * 64, c0 = blockIdx.y * 64;
  const float* ib = in + (size_t)blockIdx.z * CDIM * NDIM;
  _Float16* ob = outT + (size_t)blockIdx.z * NDIM * CDIM;
#pragma unroll
  for (int i = 0; i < 4; ++i) {
    int idx = i * 256 + t;
    int cl = idx >> 4, f4 = idx & 15;
    float4 v = *reinterpret_cast<const float4*>(
        &ib[(size_t)(c0 + cl) * NDIM + n0 + f4 * 4]);
    T[f4 * 4 + 0][cl] = (_Float16)v.x;
    T[f4 * 4 + 1][cl] = (_Float16)v.y;
    T[f4 * 4 + 2][cl] = (_Float16)v.z;
    T[f4 * 4 + 3][cl] = (_Float16)v.w;
  }
  __syncthreads();
#pragma unroll
  for (int i = 0; i < 2; ++i) {
    int idx = i * 256 + t;
    int nl = idx >> 3, ch = idx & 7;
    uint4 u = *reinterpret_cast<const uint4*>(&T[nl][ch * 8]);
    *reinterpret_cast<uint4*>(&ob[(size_t)(n0 + nl) * CDIM + c0 + ch * 8]) = u;
  }
}

// ---------------------------------------------------------------------------
// weights f32 -> fp16
// ---------------------------------------------------------------------------
__global__ void k_cvt_w16(const float* __restrict__ w,
                          _Float16* __restrict__ wh) {
  int i = (blockIdx.x * 256 + threadIdx.x) * 4;
  float4 v = *reinterpret_cast<const float4*>(&w[i]);
  wh[i] = (_Float16)v.x; wh[i + 1] = (_Float16)v.y;
  wh[i + 2] = (_Float16)v.z; wh[i + 3] = (_Float16)v.w;
}

// ---------------------------------------------------------------------------
// conv1: xf = W1*x + b1, dual-layout output:
//   xfT[b][n][o] fp16 (scalar writes) and xf[b][o][n] fp16 (via LDS transpose)
// grid (N/128, C/128, B); 128x128 tile, BK=64, 4 waves.
// ---------------------------------------------------------------------------
__global__ __launch_bounds__(256) void k_conv1_16(
    const _Float16* __restrict__ xT, const _Float16* __restrict__ w1,
    const float* __restrict__ b1, _Float16* __restrict__ xfT,
    _Float16* __restrict__ xf) {
  __shared__ __align__(16) short smem[17408];  // At[8192] Bt[8192]; Ot overlays
  short* At = smem;
  short* Bt = smem + 8192;
  const int tid = threadIdx.x;
  const int l = tid & 63, w = tid >> 6;
  const int wm = w >> 1, wn = w & 1;
  const int lr = l & 15, lh = l >> 4;
  const int i0 = blockIdx.x * 128;  // n
  const int j0 = blockIdx.y * 128;  // o
  const int b = blockIdx.z;
  const short* Ag = (const short*)(xT + (size_t)b * NDIM * CDIM);
  const short* Bg = (const short*)w1;
  f32x4 acc[4][4] = {};
  for (int c0 = 0; c0 < CDIM; c0 += 64) {
#pragma unroll
    for (int i = 0; i < 4; ++i) {
      int slot = i * 256 + tid;
      int r = slot >> 3, s = slot & 7, sp = s ^ (r & 7);
      g2lds16(Ag + (size_t)(i0 + r) * CDIM + c0 + sp * 8, At + slot * 8);
    }
#pragma unroll
    for (int i = 0; i < 4; ++i) {
      int slot = i * 256 + tid;
      int r = slot >> 3, s = slot & 7, sp = s ^ (r & 7);
      g2lds16(Bg + (size_t)(j0 + r) * CDIM + c0 + sp * 8, Bt + slot * 8);
    }
    __syncthreads();
#pragma unroll
    for (int kk = 0; kk < 2; ++kk) {
      f16x8 af[4], bf[4];
#pragma unroll
      for (int m = 0; m < 4; ++m) af[m] = ldsfrag(At, wm * 64 + m * 16 + lr, kk, lh);
#pragma unroll
      for (int nf = 0; nf < 4; ++nf) bf[nf] = ldsfrag(Bt, wn * 64 + nf * 16 + lr, kk, lh);
#pragma unroll
      for (int m = 0; m < 4; ++m)
#pragma unroll
        for (int nf = 0; nf < 4; ++nf)
          acc[m][nf] = __builtin_amdgcn_mfma_f32_16x16x32_f16(af[m], bf[nf],
                                                              acc[m][nf], 0, 0, 0);
    }
    __syncthreads();
  }
  // Epilogue: xfT scalar writes + scatter into Ot[o][n] (pad 136)
  _Float16* Otf = (_Float16*)smem;
  _Float16* ob = xfT + (size_t)b * NDIM * CDIM;
#pragma unroll
  for (int m = 0; m < 4; ++m) {
#pragma unroll
    for (int nf = 0; nf < 4; ++nf) {
      int ol = wn * 64 + nf * 16 + lr;
      float bv = b1[j0 + ol];
#pragma unroll
      for (int r = 0; r < 4; ++r) {
        int nl = wm * 64 + m * 16 + lh * 4 + r;
        _Float16 hv = (_Float16)(acc[m][nf][r] + bv);
        ob[(size_t)(i0 + nl) * CDIM + j0 + ol] = hv;
        Otf[ol * 136 + nl] = hv;
      }
    }
  }
  __syncthreads();
  _Float16* xfb = xf + (size_t)b * CDIM * NDIM;
#pragma unroll
  for (int i = 0; i < 8; ++i) {
    int seg = i * 256 + tid;
    int row = seg >> 4, cs = seg & 15;
    f16x8 v = *reinterpret_cast<const f16x8*>(&Otf[row * 136 + cs * 8]);
    *reinterpret_cast<f16x8*>(&xfb[(size_t)(j0 + row) * NDIM + i0 + cs * 8]) = v;
  }
}

// ---------------------------------------------------------------------------
// conv2: y16[b][o][n] fp16 = sum_c w2[o][c] reconT[n][c]; fused BN partial
// stats.  grid (N/128, C/128, B) — n on x so blocks sharing a reconT tile
// land on the same XCD (ids differ by 32, 32%8==0).
// ---------------------------------------------------------------------------
__global__ __launch_bounds__(256) void k_conv2_16(
    const _Float16* __restrict__ w2, const _Float16* __restrict__ reconT,
    _Float16* __restrict__ y16, float* __restrict__ bnsum,
    float* __restrict__ bnsumsq) {
  __shared__ __align__(16) short At[128 * 64];
  __shared__ __align__(16) short Bt[128 * 64];
  __shared__ float bns[128], bnq[128];
  const int tid = threadIdx.x;
  const int l = tid & 63, w = tid >> 6;
  const int wm = w >> 1, wn = w & 1;
  const int lr = l & 15, lh = l >> 4;
  const int i0 = blockIdx.y * 128;  // o
  const int j0 = blockIdx.x * 128;  // n
  const int b = blockIdx.z;
  if (tid < 128) { bns[tid] = 0.f; bnq[tid] = 0.f; }
  const short* Ag = (const short*)w2;
  const short* Bg = (const short*)(reconT + (size_t)b * NDIM * CDIM);
  f32x4 acc[4][4] = {};
  for (int c0 = 0; c0 < CDIM; c0 += 64) {
#pragma unroll
    for (int i = 0; i < 4; ++i) {
      int slot = i * 256 + tid;
      int r = slot >> 3, s = slot & 7, sp = s ^ (r & 7);
      g2lds16(Ag + (size_t)(i0 + r) * CDIM + c0 + sp * 8, At + slot * 8);
    }
#pragma unroll
    for (int i = 0; i < 4; ++i) {
      int slot = i * 256 + tid;
      int r = slot >> 3, s = slot & 7, sp = s ^ (r & 7);
      g2lds16(Bg + (size_t)(j0 + r) * CDIM + c0 + sp * 8, Bt + slot * 8);
    }
    __syncthreads();
#pragma unroll
    for (int kk = 0; kk < 2; ++kk) {
      f16x8 af[4], bf[4];
#pragma unroll
      for (int m = 0; m < 4; ++m) af[m] = ldsfrag(At, wm * 64 + m * 16 + lr, kk, lh);
#pragma unroll
      for (int nf = 0; nf < 4; ++nf) bf[nf] = ldsfrag(Bt, wn * 64 + nf * 16 + lr, kk, lh);
#pragma unroll
      for (int m = 0; m < 4; ++m)
#pragma unroll
        for (int nf = 0; nf < 4; ++nf)
          acc[m][nf] = __builtin_amdgcn_mfma_f32_16x16x32_f16(af[m], bf[nf],
                                                              acc[m][nf], 0, 0, 0);
    }
    __syncthreads();
  }
  _Float16* yb = y16 + (size_t)b * CDIM * NDIM;
#pragma unroll
  for (int m = 0; m < 4; ++m) {
#pragma unroll
    for (int r = 0; r < 4; ++r) {
      int ol = wm * 64 + m * 16 + lh * 4 + r;
      float ps = 0.f, pq = 0.f;
#pragma unroll
      for (int nf = 0; nf < 4; ++nf) {
        float v = acc[m][nf][r];
        ps += v; pq += v * v;
        yb[(size_t)(i0 + ol) * NDIM + j0 + wn * 64 + nf * 16 + lr] = (_Float16)v;
      }
#pragma unroll
      for (int d = 1; d < 16; d <<= 1) {
        ps += __shfl_xor(ps, d);
        pq += __shfl_xor(pq, d);
      }
      if (lr == 0) { atomicAdd(&bns[ol], ps); atomicAdd(&bnq[ol], pq); }
    }
  }
  __syncthreads();
  if (tid < 128) {
    atomicAdd(&bnsum[i0 + tid], bns[tid]);
    atomicAdd(&bnsumsq[i0 + tid], bnq[tid]);
  }
}

// ---------------------------------------------------------------------------
// init muT[b][k][c] fp16 = mu[c][k]
// ---------------------------------------------------------------------------
__global__ void k_init_mu16(const float* __restrict__ mu,
                            _Float16* __restrict__ muT) {
  int idx = blockIdx.x * 256 + threadIdx.x;  // 524288
  int rem = idx & 32767;
  int k = rem >> 9, c = rem & 511;
  muT[idx] = (_Float16)mu[c * KDIM + k];
}

// ---------------------------------------------------------------------------
// S1 (fp16 MFMA): logits[n][k] = sum_c xfT[n][c] muT[k][c]; z=softmax_k;
// writes z[b][n][k] (only if writeZ), zT[b][k][n] fp16, colsum[b][k].
// grid (N/128, B). 128n x 64k tile; 4 waves own 32 n-rows each.
// ---------------------------------------------------------------------------
__global__ __launch_bounds__(256) void k_s1_16(const _Float16* __restrict__ xfT,
                                               const _Float16* __restrict__ muT,
                                               _Float16* __restrict__ z,
                                               _Float16* __restrict__ zT,
                                               float* __restrict__ colsum,
                                               int writeZ) {
  __shared__ __align__(16) short At[128 * 64];
  __shared__ __align__(16) short Bt[64 * 64];
  __shared__ __align__(16) _Float16 zs[128][72];
  __shared__ float csum[4][64];
  const int tid = threadIdx.x;
  const int l = tid & 63, w = tid >> 6;
  const int lr = l & 15, lh = l >> 4;
  const int n0 = blockIdx.x * 128;
  const int b = blockIdx.y;
  const short* Ag = (const short*)(xfT + (size_t)b * NDIM * CDIM);
  const short* Bg = (const short*)(muT + (size_t)b * KDIM * CDIM);
  f32x4 acc[2][4] = {};
  for (int c0 = 0; c0 < CDIM; c0 += 64) {
#pragma unroll
    for (int i = 0; i < 4; ++i) {
      int slot = i * 256 + tid;
      int r = slot >> 3, s = slot & 7, sp = s ^ (r & 7);
      g2lds16(Ag + (size_t)(n0 + r) * CDIM + c0 + sp * 8, At + slot * 8);
    }
#pragma unroll
    for (int i = 0; i < 2; ++i) {
      int slot = i * 256 + tid;
      int r = slot >> 3, s = slot & 7, sp = s ^ (r & 7);
      g2lds16(Bg + (size_t)r * CDIM + c0 + sp * 8, Bt + slot * 8);
    }
    __syncthreads();
#pragma unroll
    for (int kk = 0; kk < 2; ++kk) {
      f16x8 af[2], bf;
#pragma unroll
      for (int nf = 0; nf < 2; ++nf)
        af[nf] = ldsfrag(At, w * 32 + nf * 16 + lr, kk, lh);
#pragma unroll
      for (int kf = 0; kf < 4; ++kf) {
        bf = ldsfrag(Bt, kf * 16 + lr, kk, lh);
#pragma unroll
        for (int nf = 0; nf < 2; ++nf)
          acc[nf][kf] = __builtin_amdgcn_mfma_f32_16x16x32_f16(af[nf], bf,
                                                               acc[nf][kf], 0, 0, 0);
      }
    }
    __syncthreads();
  }
#pragma unroll
  for (int nf = 0; nf < 2; ++nf) {
#pragma unroll
    for (int r = 0; r < 4; ++r) {
      float m = fmaxf(fmaxf(acc[nf][0][r], acc[nf][1][r]),
                      fmaxf(acc[nf][2][r], acc[nf][3][r]));
#pragma unroll
      for (int d = 8; d >= 1; d >>= 1) m = fmaxf(m, __shfl_xor(m, d));
      float e[4], s = 0.f;
#pragma unroll
      for (int kf = 0; kf < 4; ++kf) { e[kf] = __expf(acc[nf][kf][r] - m); s += e[kf]; }
#pragma unroll
      for (int d = 8; d >= 1; d >>= 1) s += __shfl_xor(s, d);
      float inv = 1.f / s;
      int row = w * 32 + nf * 16 + lh * 4 + r;
#pragma unroll
      for (int kf = 0; kf < 4; ++kf)
        zs[row][kf * 16 + lr] = (_Float16)(e[kf] * inv);
    }
  }
  __syncthreads();
  _Float16* zTb = zT + (size_t)b * KDIM * NDIM;
  if (writeZ) {
    _Float16* zb = z + (size_t)b * NDIM * KDIM;
#pragma unroll
    for (int i = 0; i < 4; ++i) {  // z[n][k]
      int idx = i * 256 + tid;
      int n = idx >> 3, ch = idx & 7;
      *reinterpret_cast<uint4*>(&zb[(size_t)(n0 + n) * KDIM + ch * 8]) =
          *reinterpret_cast<const uint4*>(&zs[n][ch * 8]);
    }
  }
#pragma unroll
  for (int i = 0; i < 4; ++i) {  // zT[k][n]
    int idx = i * 256 + tid;
    int k = idx >> 4, nch = idx & 15;
    f16x8 v;
#pragma unroll
    for (int j = 0; j < 8; ++j) v[j] = zs[nch * 8 + j][k];
    *reinterpret_cast<f16x8*>(&zTb[(size_t)k * NDIM + n0 + nch * 8]) = v;
  }
  {  // colsum: thread (q=tid>>6, k=tid&63) sums 32 rows
    int k = tid & 63, q = tid >> 6;
    float s = 0.f;
#pragma unroll
    for (int n = 0; n < 32; ++n) s += (float)zs[q * 32 + n][k];
    csum[q][k] = s;
  }
  __syncthreads();
  if (tid < 64)
    atomicAdd(&colsum[b * KDIM + tid],
              csum[0][tid] + csum[1][tid] + csum[2][tid] + csum[3][tid]);
}

// ---------------------------------------------------------------------------
// S2 (fp16 MFMA): mu_part[s][b][k][c] = sum_{n in split} zT[k][n] xf[c][n]
// (fp16 store; f32 accum in registers)  grid (C/128, NSPLIT, B)
// ---------------------------------------------------------------------------
__global__ __launch_bounds__(256) void k_s2_16(const _Float16* __restrict__ zT,
                                               const _Float16* __restrict__ xf,
                                               _Float16* __restrict__ mupart) {
  __shared__ __align__(16) short At[64 * 64];
  __shared__ __align__(16) short Bt[128 * 64];
  const int tid = threadIdx.x;
  const int l = tid & 63, w = tid >> 6;
  const int lr = l & 15, lh = l >> 4;
  const int c0 = blockIdx.x * 128;
  const int split = blockIdx.y;
  const int b = blockIdx.z;
  const short* Ag = (const short*)(zT + (size_t)b * KDIM * NDIM);
  const short* Bg = (const short*)(xf + (size_t)b * CDIM * NDIM);
  f32x4 acc[4][2] = {};
  for (int st = 0; st < NDIM / NSPLIT / 64; ++st) {
    const int nb = split * (NDIM / NSPLIT) + st * 64;
#pragma unroll
    for (int i = 0; i < 2; ++i) {
      int slot = i * 256 + tid;
      int r = slot >> 3, s = slot & 7, sp = s ^ (r & 7);
      g2lds16(Ag + (size_t)r * NDIM + nb + sp * 8, At + slot * 8);
    }
#pragma unroll
    for (int i = 0; i < 4; ++i) {
      int slot = i * 256 + tid;
      int r = slot >> 3, s = slot & 7, sp = s ^ (r & 7);
      g2lds16(Bg + (size_t)(c0 + r) * NDIM + nb + sp * 8, Bt + slot * 8);
    }
    __syncthreads();
#pragma unroll
    for (int kk = 0; kk < 2; ++kk) {
      f16x8 bf[2], af;
#pragma unroll
      for (int cf = 0; cf < 2; ++cf)
        bf[cf] = ldsfrag(Bt, w * 32 + cf * 16 + lr, kk, lh);
#pragma unroll
      for (int kf = 0; kf < 4; ++kf) {
        af = ldsfrag(At, kf * 16 + lr, kk, lh);
#pragma unroll
        for (int cf = 0; cf < 2; ++cf)
          acc[kf][cf] = __builtin_amdgcn_mfma_f32_16x16x32_f16(af, bf[cf],
                                                               acc[kf][cf], 0, 0, 0);
      }
    }
    __syncthreads();
  }
  _Float16* mp = mupart + ((size_t)(split * BDIM + b) * KDIM) * CDIM;
#pragma unroll
  for (int kf = 0; kf < 4; ++kf) {
    int k = kf * 16 + lh * 4;
#pragma unroll
    for (int r = 0; r < 4; ++r)
#pragma unroll
      for (int cf = 0; cf < 2; ++cf)
        mp[(size_t)(k + r) * CDIM + c0 + w * 32 + cf * 16 + lr] =
            (_Float16)acc[kf][cf][r];
  }
}

// ---------------------------------------------------------------------------
// S2 reduce: v[c] = sum_s mu_part (fp16 in, f32 sum); t = v*scs[k];
// out = t/(1e-6+|t|_2).  Also zeroes colsum for the next stage.
// ---------------------------------------------------------------------------
__global__ __launch_bounds__(256) void k_s2red(const _Float16* __restrict__ mupart,
                                               float* __restrict__ colsum,
                                               _Float16* __restrict__ muT,
                                               _Float16* __restrict__ mu_ck) {
  __shared__ float red[4];
  const int tid = threadIdx.x;
  const int b = blockIdx.x >> 6, k = blockIdx.x & 63;
  const float csv = colsum[b * KDIM + k];  // all threads read before zeroing
  float v0 = 0.f, v1 = 0.f;
#pragma unroll
  for (int s = 0; s < NSPLIT; ++s) {
    const _Float16* mp = mupart + ((size_t)(s * BDIM + b) * KDIM + k) * CDIM;
    v0 += (float)mp[tid];
    v1 += (float)mp[tid + 256];
  }
  float ssq = v0 * v0 + v1 * v1;
#pragma unroll
  for (int d = 32; d >= 1; d >>= 1) ssq += __shfl_down(ssq, d);
  if ((tid & 63) == 0) red[tid >> 6] = ssq;
  __syncthreads();
  if (tid == 0) colsum[b * KDIM + k] = 0.f;
  float tot = red[0] + red[1] + red[2] + red[3];
  float scs = 1.f / (1e-6f + csv);
  float inv = scs / (1e-6f + scs * sqrtf(tot));
  _Float16 o0 = (_Float16)(v0 * inv), o1 = (_Float16)(v1 * inv);
  muT[((size_t)b * KDIM + k) * CDIM + tid] = o0;
  muT[((size_t)b * KDIM + k) * CDIM + tid + 256] = o1;
  mu_ck[((size_t)b * CDIM + tid) * KDIM + k] = o0;
  mu_ck[((size_t)b * CDIM + tid + 256) * KDIM + k] = o1;
}

// ---------------------------------------------------------------------------
// recon (fp16 MFMA): reconT[n][c] = relu(sum_k z[n][k] mu_ck[c][k])
// grid (N/128, C/128, B)
// ---------------------------------------------------------------------------
__global__ __launch_bounds__(256) void k_recon16(const _Float16* __restrict__ z,
                                                 const _Float16* __restrict__ mu_ck,
                                                 _Float16* __restrict__ reconT) {
  __shared__ __align__(16) short Az[128 * 64];
  __shared__ __align__(16) short Bm[128 * 64];
  const int tid = threadIdx.x;
  const int l = tid & 63, w = tid >> 6;
  const int wm = w >> 1, wn = w & 1;
  const int lr = l & 15, lh = l >> 4;
  const int n0 = blockIdx.x * 128;
  const int c0 = blockIdx.y * 128;
  const int b = blockIdx.z;
  const short* Ag = (const short*)(z + (size_t)b * NDIM * KDIM);
  const short* Bg = (const short*)(mu_ck + (size_t)b * CDIM * KDIM);
#pragma unroll
  for (int i = 0; i < 4; ++i) {
    int slot = i * 256 + tid;
    int r = slot >> 3, s = slot & 7, sp = s ^ (r & 7);
    g2lds16(Ag + (size_t)(n0 + r) * KDIM + sp * 8, Az + slot * 8);
  }
#pragma unroll
  for (int i = 0; i < 4; ++i) {
    int slot = i * 256 + tid;
    int r = slot >> 3, s = slot & 7, sp = s ^ (r & 7);
    g2lds16(Bg + (size_t)(c0 + r) * KDIM + sp * 8, Bm + slot * 8);
  }
  __syncthreads();
  f32x4 acc[4][4] = {};
#pragma unroll
  for (int kk = 0; kk < 2; ++kk) {
    f16x8 af[4], bf[4];
#pragma unroll
    for (int m = 0; m < 4; ++m) af[m] = ldsfrag(Az, wm * 64 + m * 16 + lr, kk, lh);
#pragma unroll
    for (int nf = 0; nf < 4; ++nf) bf[nf] = ldsfrag(Bm, wn * 64 + nf * 16 + lr, kk, lh);
#pragma unroll
    for (int m = 0; m < 4; ++m)
#pragma unroll
      for (int nf = 0; nf < 4; ++nf)
        acc[m][nf] = __builtin_amdgcn_mfma_f32_16x16x32_f16(af[m], bf[nf],
                                                            acc[m][nf], 0, 0, 0);
  }
  _Float16* ob = reconT + (size_t)b * NDIM * CDIM;
#pragma unroll
  for (int m = 0; m < 4; ++m) {
#pragma unroll
    for (int r = 0; r < 4; ++r) {
      int n = n0 + wm * 64 + m * 16 + lh * 4 + r;
#pragma unroll
      for (int nf = 0; nf < 4; ++nf) {
        int c = c0 + wn * 64 + nf * 16 + lr;
        ob[(size_t)n * CDIM + c] = (_Float16)fmaxf(acc[m][nf][r], 0.f);
      }
    }
  }
}

// ---------------------------------------------------------------------------
// final: out = relu((y-mean)*rsqrt(var+eps)*gamma + beta + x), y fp16
// ---------------------------------------------------------------------------
__global__ void k_final(float* __restrict__ out, const _Float16* __restrict__ y16,
                        const float* __restrict__ x,
                        const float* __restrict__ bnsum,
                        const float* __restrict__ bnsumsq,
                        const float* __restrict__ gamma,
                        const float* __restrict__ beta) {
  const float invM = 1.f / (BDIM * (float)NDIM);
  const size_t total4 = (size_t)BDIM * CDIM * NDIM / 4;
  for (size_t i4 = (size_t)blockIdx.x * 256 + threadIdx.x; i4 < total4;
       i4 += (size_t)gridDim.x * 256) {
    int c = (int)((i4 >> 10) & (CDIM - 1));
    float mean = bnsum[c] * invM;
    float var = bnsumsq[c] * invM - mean * mean;
    float sc = rsqrtf(var + 1e-5f) * gamma[c];
    float sh = beta[c] - mean * sc;
    f16x4 yv = *reinterpret_cast<const f16x4*>(&y16[i4 * 4]);
    float4 xv = reinterpret_cast<const float4*>(x)[i4];
    float4 o;
    o.x = fmaxf(fmaf((float)yv[0], sc, sh) + xv.x, 0.f);
    o.y = fmaxf(fmaf((float)yv[1], sc, sh) + xv.y, 0.f);
    o.z = fmaxf(fmaf((float)yv[2], sc, sh) + xv.z, 0.f);
    o.w = fmaxf(fmaf((float)yv[3], sc, sh) + xv.w, 0.f);
    reinterpret_cast<float4*>(out)[i4] = o;
  }
}

// ---------------------------------------------------------------------------
extern "C" void kernel_launch(void* const* d_in, const int* in_sizes, int n_in,
                              void* d_out, int out_size, void* d_ws,
                              size_t ws_size, hipStream_t stream) {
  const float* x = (const float*)d_in[0];
  const float* mu = (const float*)d_in[1];
  const float* w1 = (const float*)d_in[2];
  const float* b1 = (const float*)d_in[3];
  const float* w2 = (const float*)d_in[4];
  const float* gamma = (const float*)d_in[5];
  const float* beta = (const float*)d_in[6];
  float* out = (float*)d_out;

  // xf dual copies live in d_out until k_final overwrites it.
  _Float16* xfT = (_Float16*)d_out;              // [B][N][C]
  _Float16* xf = (_Float16*)d_out + 33554432;    // [B][C][N]

  _Float16* wsH = (_Float16*)d_ws;
  _Float16* xT = wsH;                            // [B][N][C] (reused as reconT)
  _Float16* reconT = wsH;
  _Float16* z = wsH + 33554432;                  // [B][N][K]
  _Float16* zT = z + 4194304;                    // [B][K][N]
  _Float16* muT = zT + 4194304;                  // [B][K][C]
  _Float16* mu_ck = muT + 524288;                // [B][C][K]
  _Float16* w1h = mu_ck + 524288;                // [C][C]
  _Float16* w2h = w1h + 262144;
  _Float16* mupart = w2h + 262144;               // [S=8][B][K][C] fp16
  float* wsF = (float*)(mupart + 4194304);
  float* colsum = wsF;                           // [B][K]
  float* bnsum = colsum + 1024;                  // [C]
  float* bnsumsq = bnsum + 512;                  // [C]
  _Float16* y16 = (_Float16*)(bnsumsq + 512);    // [B][C][N] fp16

  k_cvtT16<<<dim3(NDIM / 64, CDIM / 64, BDIM), 256, 0, stream>>>(x, xT);
  k_cvt_w16<<<CDIM * CDIM / 1024, 256, 0, stream>>>(w1, w1h);
  k_cvt_w16<<<CDIM * CDIM / 1024, 256, 0, stream>>>(w2, w2h);

  k_conv1_16<<<dim3(NDIM / 128, CDIM / 128, BDIM), 256, 0, stream>>>(
      xT, w1h, b1, xfT, xf);
  k_init_mu16<<<2048, 256, 0, stream>>>(mu, muT);

  // colsum zeroed once; k_s2red re-zeroes it for subsequent stages.
  hipMemsetAsync(colsum, 0, 1024 * sizeof(float), stream);
  for (int s = 0; s < 3; ++s) {
    k_s1_16<<<dim3(NDIM / 128, BDIM), 256, 0, stream>>>(xfT, muT, z, zT, colsum,
                                                        s == 2 ? 1 : 0);
    k_s2_16<<<dim3(CDIM / 128, NSPLIT, BDIM), 256, 0, stream>>>(zT, xf, mupart);
    k_s2red<<<KDIM * BDIM, 256, 0, stream>>>(mupart, colsum, muT, mu_ck);
  }

  k_recon16<<<dim3(NDIM / 128, CDIM / 128, BDIM), 256, 0, stream>>>(z, mu_ck,
                                                                    reconT);
  hipMemsetAsync(bnsum, 0, 1024 * sizeof(float), stream);
  k_conv2_16<<<dim3(NDIM / 128, CDIM / 128, BDIM), 256, 0, stream>>>(
      w2h, reconT, y16, bnsum, bnsumsq);

  k_final<<<4096, 256, 0, stream>>>(out, y16, x, bnsum, bnsumsq, gamma, beta);
}

// Round 12
// 363.838 us; speedup vs baseline: 1.1370x; 1.0202x over previous
//
#include <hip/hip_runtime.h>
#include <math.h>

#define CDIM 512
#define NDIM 4096
#define KDIM 64
#define BDIM 16
#define NSPLIT 8

typedef __attribute__((ext_vector_type(8))) _Float16 f16x8;
typedef __attribute__((ext_vector_type(4))) _Float16 f16x4;
typedef __attribute__((ext_vector_type(4))) float f32x4;

__device__ __forceinline__ void g2lds16(const void* g, void* l) {
  __builtin_amdgcn_global_load_lds(
      (const __attribute__((address_space(1))) int*)g,
      (__attribute__((address_space(3))) int*)l, 16, 0, 0);
}

__device__ __forceinline__ f16x8 ldsfrag(const short* base, int row, int kk,
                                         int lh) {
  int slot = (kk * 4 + lh) ^ (row & 7);
  return *reinterpret_cast<const f16x8*>(&base[row * 64 + slot * 8]);
}

// ---------------------------------------------------------------------------
// x [b][c][n] f32 -> xT [b][n][c] fp16.  grid (N/64, C/64, B)
// LDS tile swizzled: logical col-group G of row n stored at physical group
// G ^ ((n>>2)&7) — write conflicts 16-way -> 4-way, reads at b128 minimum.
// ---------------------------------------------------------------------------
__global__ __launch_bounds__(256) void k_cvtT16(const float* __restrict__ in,
                                                _Float16* __restrict__ outT) {
  __shared__ __align__(16) _Float16 T[64 * 64];
  const int t = threadIdx.x;
  const int n0 = blockIdx.x * 64, c0 = blockIdx.y * 64;
  const float* ib = in + (size_t)blockIdx.z * CDIM * NDIM;
  _Float16* ob = outT + (size_t)blockIdx.z * NDIM * CDIM;
#pragma unroll
  for (int i = 0; i < 4; ++i) {
    int idx = i * 256 + t;
    int cl = idx >> 4, f4 = idx & 15;
    float4 v = *reinterpret_cast<const float4*>(
        &ib[(size_t)(c0 + cl) * NDIM + n0 + f4 * 4]);
    // rows n = f4*4+j  ->  (n>>2)&7 == f4&7 for all j
    int colp = ((((cl >> 3) ^ (f4 & 7)) << 3) + (cl & 7));
    T[(f4 * 4 + 0) * 64 + colp] = (_Float16)v.x;
    T[(f4 * 4 + 1) * 64 + colp] = (_Float16)v.y;
    T[(f4 * 4 + 2) * 64 + colp] = (_Float16)v.z;
    T[(f4 * 4 + 3) * 64 + colp] = (_Float16)v.w;
  }
  __syncthreads();
#pragma unroll
  for (int i = 0; i < 2; ++i) {
    int idx = i * 256 + t;
    int nl = idx >> 3, ch = idx & 7;
    int g = (nl >> 2) & 7;
    uint4 u = *reinterpret_cast<const uint4*>(&T[nl * 64 + ((ch ^ g) << 3)]);
    *reinterpret_cast<uint4*>(&ob[(size_t)(n0 + nl) * CDIM + c0 + ch * 8]) = u;
  }
}

// ---------------------------------------------------------------------------
// prep (one launch): w1->fp16, w2->fp16, muT init, zero colsum/bnsum/bnsumsq.
// grid 2561 blocks x 256.
// ---------------------------------------------------------------------------
__global__ void k_prep(const float* __restrict__ w1, const float* __restrict__ w2,
                       const float* __restrict__ mu, _Float16* __restrict__ w1h,
                       _Float16* __restrict__ w2h, _Float16* __restrict__ muT,
                       float* __restrict__ zeroed /*colsum+bnsum+bnsumsq*/) {
  int blk = blockIdx.x;
  if (blk < 256) {  // w1
    int i = (blk * 256 + threadIdx.x) * 4;
    float4 v = *reinterpret_cast<const float4*>(&w1[i]);
    w1h[i] = (_Float16)v.x; w1h[i + 1] = (_Float16)v.y;
    w1h[i + 2] = (_Float16)v.z; w1h[i + 3] = (_Float16)v.w;
  } else if (blk < 512) {  // w2
    int i = ((blk - 256) * 256 + threadIdx.x) * 4;
    float4 v = *reinterpret_cast<const float4*>(&w2[i]);
    w2h[i] = (_Float16)v.x; w2h[i + 1] = (_Float16)v.y;
    w2h[i + 2] = (_Float16)v.z; w2h[i + 3] = (_Float16)v.w;
  } else if (blk < 2560) {  // muT[b][k][c] = mu[c][k]
    int idx = (blk - 512) * 256 + threadIdx.x;  // 524288
    int rem = idx & 32767;
    int k = rem >> 9, c = rem & 511;
    muT[idx] = (_Float16)mu[c * KDIM + k];
  } else {  // zero colsum[1024] + bnsum[512] + bnsumsq[512]
    zeroed[threadIdx.x * 8 + 0] = 0.f; zeroed[threadIdx.x * 8 + 1] = 0.f;
    zeroed[threadIdx.x * 8 + 2] = 0.f; zeroed[threadIdx.x * 8 + 3] = 0.f;
    zeroed[threadIdx.x * 8 + 4] = 0.f; zeroed[threadIdx.x * 8 + 5] = 0.f;
    zeroed[threadIdx.x * 8 + 6] = 0.f; zeroed[threadIdx.x * 8 + 7] = 0.f;
  }
}

// ---------------------------------------------------------------------------
// conv1: xf = W1*x + b1, dual-layout output:
//   xfT[b][n][o] fp16 (scalar writes) and xf[b][o][n] fp16 (via LDS transpose)
// grid (N/128, C/128, B); 128x128 tile, BK=64, 4 waves.
// ---------------------------------------------------------------------------
__global__ __launch_bounds__(256) void k_conv1_16(
    const _Float16* __restrict__ xT, const _Float16* __restrict__ w1,
    const float* __restrict__ b1, _Float16* __restrict__ xfT,
    _Float16* __restrict__ xf) {
  __shared__ __align__(16) short smem[17408];  // At[8192] Bt[8192]; Ot overlays
  short* At = smem;
  short* Bt = smem + 8192;
  const int tid = threadIdx.x;
  const int l = tid & 63, w = tid >> 6;
  const int wm = w >> 1, wn = w & 1;
  const int lr = l & 15, lh = l >> 4;
  const int i0 = blockIdx.x * 128;  // n
  const int j0 = blockIdx.y * 128;  // o
  const int b = blockIdx.z;
  const short* Ag = (const short*)(xT + (size_t)b * NDIM * CDIM);
  const short* Bg = (const short*)w1;
  f32x4 acc[4][4] = {};
  for (int c0 = 0; c0 < CDIM; c0 += 64) {
#pragma unroll
    for (int i = 0; i < 4; ++i) {
      int slot = i * 256 + tid;
      int r = slot >> 3, s = slot & 7, sp = s ^ (r & 7);
      g2lds16(Ag + (size_t)(i0 + r) * CDIM + c0 + sp * 8, At + slot * 8);
    }
#pragma unroll
    for (int i = 0; i < 4; ++i) {
      int slot = i * 256 + tid;
      int r = slot >> 3, s = slot & 7, sp = s ^ (r & 7);
      g2lds16(Bg + (size_t)(j0 + r) * CDIM + c0 + sp * 8, Bt + slot * 8);
    }
    __syncthreads();
#pragma unroll
    for (int kk = 0; kk < 2; ++kk) {
      f16x8 af[4], bf[4];
#pragma unroll
      for (int m = 0; m < 4; ++m) af[m] = ldsfrag(At, wm * 64 + m * 16 + lr, kk, lh);
#pragma unroll
      for (int nf = 0; nf < 4; ++nf) bf[nf] = ldsfrag(Bt, wn * 64 + nf * 16 + lr, kk, lh);
#pragma unroll
      for (int m = 0; m < 4; ++m)
#pragma unroll
        for (int nf = 0; nf < 4; ++nf)
          acc[m][nf] = __builtin_amdgcn_mfma_f32_16x16x32_f16(af[m], bf[nf],
                                                              acc[m][nf], 0, 0, 0);
    }
    __syncthreads();
  }
  // Epilogue: xfT scalar writes + scatter into Ot[o][n] (pad 136)
  _Float16* Otf = (_Float16*)smem;
  _Float16* ob = xfT + (size_t)b * NDIM * CDIM;
#pragma unroll
  for (int m = 0; m < 4; ++m) {
#pragma unroll
    for (int nf = 0; nf < 4; ++nf) {
      int ol = wn * 64 + nf * 16 + lr;
      float bv = b1[j0 + ol];
#pragma unroll
      for (int r = 0; r < 4; ++r) {
        int nl = wm * 64 + m * 16 + lh * 4 + r;
        _Float16 hv = (_Float16)(acc[m][nf][r] + bv);
        ob[(size_t)(i0 + nl) * CDIM + j0 + ol] = hv;
        Otf[ol * 136 + nl] = hv;
      }
    }
  }
  __syncthreads();
  _Float16* xfb = xf + (size_t)b * CDIM * NDIM;
#pragma unroll
  for (int i = 0; i < 8; ++i) {
    int seg = i * 256 + tid;
    int row = seg >> 4, cs = seg & 15;
    f16x8 v = *reinterpret_cast<const f16x8*>(&Otf[row * 136 + cs * 8]);
    *reinterpret_cast<f16x8*>(&xfb[(size_t)(j0 + row) * NDIM + i0 + cs * 8]) = v;
  }
}

// ---------------------------------------------------------------------------
// conv2: y16[b][o][n] fp16 = sum_c w2[o][c] reconT[n][c]; fused BN partial
// stats.  grid (N/128, C/128, B) — n on x so blocks sharing a reconT tile
// land on the same XCD (ids differ by 32, 32%8==0).
// ---------------------------------------------------------------------------
__global__ __launch_bounds__(256) void k_conv2_16(
    const _Float16* __restrict__ w2, const _Float16* __restrict__ reconT,
    _Float16* __restrict__ y16, float* __restrict__ bnsum,
    float* __restrict__ bnsumsq) {
  __shared__ __align__(16) short At[128 * 64];
  __shared__ __align__(16) short Bt[128 * 64];
  __shared__ float bns[128], bnq[128];
  const int tid = threadIdx.x;
  const int l = tid & 63, w = tid >> 6;
  const int wm = w >> 1, wn = w & 1;
  const int lr = l & 15, lh = l >> 4;
  const int i0 = blockIdx.y * 128;  // o
  const int j0 = blockIdx.x * 128;  // n
  const int b = blockIdx.z;
  if (tid < 128) { bns[tid] = 0.f; bnq[tid] = 0.f; }
  const short* Ag = (const short*)w2;
  const short* Bg = (const short*)(reconT + (size_t)b * NDIM * CDIM);
  f32x4 acc[4][4] = {};
  for (int c0 = 0; c0 < CDIM; c0 += 64) {
#pragma unroll
    for (int i = 0; i < 4; ++i) {
      int slot = i * 256 + tid;
      int r = slot >> 3, s = slot & 7, sp = s ^ (r & 7);
      g2lds16(Ag + (size_t)(i0 + r) * CDIM + c0 + sp * 8, At + slot * 8);
    }
#pragma unroll
    for (int i = 0; i < 4; ++i) {
      int slot = i * 256 + tid;
      int r = slot >> 3, s = slot & 7, sp = s ^ (r & 7);
      g2lds16(Bg + (size_t)(j0 + r) * CDIM + c0 + sp * 8, Bt + slot * 8);
    }
    __syncthreads();
#pragma unroll
    for (int kk = 0; kk < 2; ++kk) {
      f16x8 af[4], bf[4];
#pragma unroll
      for (int m = 0; m < 4; ++m) af[m] = ldsfrag(At, wm * 64 + m * 16 + lr, kk, lh);
#pragma unroll
      for (int nf = 0; nf < 4; ++nf) bf[nf] = ldsfrag(Bt, wn * 64 + nf * 16 + lr, kk, lh);
#pragma unroll
      for (int m = 0; m < 4; ++m)
#pragma unroll
        for (int nf = 0; nf < 4; ++nf)
          acc[m][nf] = __builtin_amdgcn_mfma_f32_16x16x32_f16(af[m], bf[nf],
                                                              acc[m][nf], 0, 0, 0);
    }
    __syncthreads();
  }
  _Float16* yb = y16 + (size_t)b * CDIM * NDIM;
#pragma unroll
  for (int m = 0; m < 4; ++m) {
#pragma unroll
    for (int r = 0; r < 4; ++r) {
      int ol = wm * 64 + m * 16 + lh * 4 + r;
      float ps = 0.f, pq = 0.f;
#pragma unroll
      for (int nf = 0; nf < 4; ++nf) {
        float v = acc[m][nf][r];
        ps += v; pq += v * v;
        yb[(size_t)(i0 + ol) * NDIM + j0 + wn * 64 + nf * 16 + lr] = (_Float16)v;
      }
#pragma unroll
      for (int d = 1; d < 16; d <<= 1) {
        ps += __shfl_xor(ps, d);
        pq += __shfl_xor(pq, d);
      }
      if (lr == 0) { atomicAdd(&bns[ol], ps); atomicAdd(&bnq[ol], pq); }
    }
  }
  __syncthreads();
  if (tid < 128) {
    atomicAdd(&bnsum[i0 + tid], bns[tid]);
    atomicAdd(&bnsumsq[i0 + tid], bnq[tid]);
  }
}

// ---------------------------------------------------------------------------
// S1 (fp16 MFMA): logits[n][k] = sum_c xfT[n][c] muT[k][c]; z=softmax_k;
// writes z[b][n][k] (only if writeZ), zT[b][k][n] fp16, colsum[b][k].
// grid (N/128, B). 128n x 64k tile; 4 waves own 32 n-rows each.
// ---------------------------------------------------------------------------
__global__ __launch_bounds__(256) void k_s1_16(const _Float16* __restrict__ xfT,
                                               const _Float16* __restrict__ muT,
                                               _Float16* __restrict__ z,
                                               _Float16* __restrict__ zT,
                                               float* __restrict__ colsum,
                                               int writeZ) {
  __shared__ __align__(16) short At[128 * 64];
  __shared__ __align__(16) short Bt[64 * 64];
  __shared__ __align__(16) _Float16 zs[128][72];
  __shared__ float csum[4][64];
  const int tid = threadIdx.x;
  const int l = tid & 63, w = tid >> 6;
  const int lr = l & 15, lh = l >> 4;
  const int n0 = blockIdx.x * 128;
  const int b = blockIdx.y;
  const short* Ag = (const short*)(xfT + (size_t)b * NDIM * CDIM);
  const short* Bg = (const short*)(muT + (size_t)b * KDIM * CDIM);
  f32x4 acc[2][4] = {};
  for (int c0 = 0; c0 < CDIM; c0 += 64) {
#pragma unroll
    for (int i = 0; i < 4; ++i) {
      int slot = i * 256 + tid;
      int r = slot >> 3, s = slot & 7, sp = s ^ (r & 7);
      g2lds16(Ag + (size_t)(n0 + r) * CDIM + c0 + sp * 8, At + slot * 8);
    }
#pragma unroll
    for (int i = 0; i < 2; ++i) {
      int slot = i * 256 + tid;
      int r = slot >> 3, s = slot & 7, sp = s ^ (r & 7);
      g2lds16(Bg + (size_t)r * CDIM + c0 + sp * 8, Bt + slot * 8);
    }
    __syncthreads();
#pragma unroll
    for (int kk = 0; kk < 2; ++kk) {
      f16x8 af[2], bf;
#pragma unroll
      for (int nf = 0; nf < 2; ++nf)
        af[nf] = ldsfrag(At, w * 32 + nf * 16 + lr, kk, lh);
#pragma unroll
      for (int kf = 0; kf < 4; ++kf) {
        bf = ldsfrag(Bt, kf * 16 + lr, kk, lh);
#pragma unroll
        for (int nf = 0; nf < 2; ++nf)
          acc[nf][kf] = __builtin_amdgcn_mfma_f32_16x16x32_f16(af[nf], bf,
                                                               acc[nf][kf], 0, 0, 0);
      }
    }
    __syncthreads();
  }
#pragma unroll
  for (int nf = 0; nf < 2; ++nf) {
#pragma unroll
    for (int r = 0; r < 4; ++r) {
      float m = fmaxf(fmaxf(acc[nf][0][r], acc[nf][1][r]),
                      fmaxf(acc[nf][2][r], acc[nf][3][r]));
#pragma unroll
      for (int d = 8; d >= 1; d >>= 1) m = fmaxf(m, __shfl_xor(m, d));
      float e[4], s = 0.f;
#pragma unroll
      for (int kf = 0; kf < 4; ++kf) { e[kf] = __expf(acc[nf][kf][r] - m); s += e[kf]; }
#pragma unroll
      for (int d = 8; d >= 1; d >>= 1) s += __shfl_xor(s, d);
      float inv = 1.f / s;
      int row = w * 32 + nf * 16 + lh * 4 + r;
#pragma unroll
      for (int kf = 0; kf < 4; ++kf)
        zs[row][kf * 16 + lr] = (_Float16)(e[kf] * inv);
    }
  }
  __syncthreads();
  _Float16* zTb = zT + (size_t)b * KDIM * NDIM;
  if (writeZ) {
    _Float16* zb = z + (size_t)b * NDIM * KDIM;
#pragma unroll
    for (int i = 0; i < 4; ++i) {  // z[n][k]
      int idx = i * 256 + tid;
      int n = idx >> 3, ch = idx & 7;
      *reinterpret_cast<uint4*>(&zb[(size_t)(n0 + n) * KDIM + ch * 8]) =
          *reinterpret_cast<const uint4*>(&zs[n][ch * 8]);
    }
  }
#pragma unroll
  for (int i = 0; i < 4; ++i) {  // zT[k][n]
    int idx = i * 256 + tid;
    int k = idx >> 4, nch = idx & 15;
    f16x8 v;
#pragma unroll
    for (int j = 0; j < 8; ++j) v[j] = zs[nch * 8 + j][k];
    *reinterpret_cast<f16x8*>(&zTb[(size_t)k * NDIM + n0 + nch * 8]) = v;
  }
  {  // colsum: thread (q=tid>>6, k=tid&63) sums 32 rows
    int k = tid & 63, q = tid >> 6;
    float s = 0.f;
#pragma unroll
    for (int n = 0; n < 32; ++n) s += (float)zs[q * 32 + n][k];
    csum[q][k] = s;
  }
  __syncthreads();
  if (tid < 64)
    atomicAdd(&colsum[b * KDIM + tid],
              csum[0][tid] + csum[1][tid] + csum[2][tid] + csum[3][tid]);
}

// ---------------------------------------------------------------------------
// S2 (fp16 MFMA): mu_part[s][b][k][c] = sum_{n in split} zT[k][n] xf[c][n]
// (fp16 store; f32 accum in registers)  grid (C/128, NSPLIT, B)
// ---------------------------------------------------------------------------
__global__ __launch_bounds__(256) void k_s2_16(const _Float16* __restrict__ zT,
                                               const _Float16* __restrict__ xf,
                                               _Float16* __restrict__ mupart) {
  __shared__ __align__(16) short At[64 * 64];
  __shared__ __align__(16) short Bt[128 * 64];
  const int tid = threadIdx.x;
  const int l = tid & 63, w = tid >> 6;
  const int lr = l & 15, lh = l >> 4;
  const int c0 = blockIdx.x * 128;
  const int split = blockIdx.y;
  const int b = blockIdx.z;
  const short* Ag = (const short*)(zT + (size_t)b * KDIM * NDIM);
  const short* Bg = (const short*)(xf + (size_t)b * CDIM * NDIM);
  f32x4 acc[4][2] = {};
  for (int st = 0; st < NDIM / NSPLIT / 64; ++st) {
    const int nb = split * (NDIM / NSPLIT) + st * 64;
#pragma unroll
    for (int i = 0; i < 2; ++i) {
      int slot = i * 256 + tid;
      int r = slot >> 3, s = slot & 7, sp = s ^ (r & 7);
      g2lds16(Ag + (size_t)r * NDIM + nb + sp * 8, At + slot * 8);
    }
#pragma unroll
    for (int i = 0; i < 4; ++i) {
      int slot = i * 256 + tid;
      int r = slot >> 3, s = slot & 7, sp = s ^ (r & 7);
      g2lds16(Bg + (size_t)(c0 + r) * NDIM + nb + sp * 8, Bt + slot * 8);
    }
    __syncthreads();
#pragma unroll
    for (int kk = 0; kk < 2; ++kk) {
      f16x8 bf[2], af;
#pragma unroll
      for (int cf = 0; cf < 2; ++cf)
        bf[cf] = ldsfrag(Bt, w * 32 + cf * 16 + lr, kk, lh);
#pragma unroll
      for (int kf = 0; kf < 4; ++kf) {
        af = ldsfrag(At, kf * 16 + lr, kk, lh);
#pragma unroll
        for (int cf = 0; cf < 2; ++cf)
          acc[kf][cf] = __builtin_amdgcn_mfma_f32_16x16x32_f16(af, bf[cf],
                                                               acc[kf][cf], 0, 0, 0);
      }
    }
    __syncthreads();
  }
  _Float16* mp = mupart + ((size_t)(split * BDIM + b) * KDIM) * CDIM;
#pragma unroll
  for (int kf = 0; kf < 4; ++kf) {
    int k = kf * 16 + lh * 4;
#pragma unroll
    for (int r = 0; r < 4; ++r)
#pragma unroll
      for (int cf = 0; cf < 2; ++cf)
        mp[(size_t)(k + r) * CDIM + c0 + w * 32 + cf * 16 + lr] =
            (_Float16)acc[kf][cf][r];
  }
}

// ---------------------------------------------------------------------------
// S2 reduce: v[c] = sum_s mu_part (fp16 in, f32 sum); t = v*scs[k];
// out = t/(1e-6+|t|_2).  Also zeroes colsum for the next stage.
// ---------------------------------------------------------------------------
__global__ __launch_bounds__(256) void k_s2red(const _Float16* __restrict__ mupart,
                                               float* __restrict__ colsum,
                                               _Float16* __restrict__ muT,
                                               _Float16* __restrict__ mu_ck) {
  __shared__ float red[4];
  const int tid = threadIdx.x;
  const int b = blockIdx.x >> 6, k = blockIdx.x & 63;
  const float csv = colsum[b * KDIM + k];  // all threads read before zeroing
  float v0 = 0.f, v1 = 0.f;
#pragma unroll
  for (int s = 0; s < NSPLIT; ++s) {
    const _Float16* mp = mupart + ((size_t)(s * BDIM + b) * KDIM + k) * CDIM;
    v0 += (float)mp[tid];
    v1 += (float)mp[tid + 256];
  }
  float ssq = v0 * v0 + v1 * v1;
#pragma unroll
  for (int d = 32; d >= 1; d >>= 1) ssq += __shfl_down(ssq, d);
  if ((tid & 63) == 0) red[tid >> 6] = ssq;
  __syncthreads();
  if (tid == 0) colsum[b * KDIM + k] = 0.f;
  float tot = red[0] + red[1] + red[2] + red[3];
  float scs = 1.f / (1e-6f + csv);
  float inv = scs / (1e-6f + scs * sqrtf(tot));
  _Float16 o0 = (_Float16)(v0 * inv), o1 = (_Float16)(v1 * inv);
  muT[((size_t)b * KDIM + k) * CDIM + tid] = o0;
  muT[((size_t)b * KDIM + k) * CDIM + tid + 256] = o1;
  mu_ck[((size_t)b * CDIM + tid) * KDIM + k] = o0;
  mu_ck[((size_t)b * CDIM + tid + 256) * KDIM + k] = o1;
}

// ---------------------------------------------------------------------------
// recon (fp16 MFMA): reconT[n][c] = relu(sum_k z[n][k] mu_ck[c][k])
// grid (N/128, C/128, B)
// ---------------------------------------------------------------------------
__global__ __launch_bounds__(256) void k_recon16(const _Float16* __restrict__ z,
                                                 const _Float16* __restrict__ mu_ck,
                                                 _Float16* __restrict__ reconT) {
  __shared__ __align__(16) short Az[128 * 64];
  __shared__ __align__(16) short Bm[128 * 64];
  const int tid = threadIdx.x;
  const int l = tid & 63, w = tid >> 6;
  const int wm = w >> 1, wn = w & 1;
  const int lr = l & 15, lh = l >> 4;
  const int n0 = blockIdx.x * 128;
  const int c0 = blockIdx.y * 128;
  const int b = blockIdx.z;
  const short* Ag = (const short*)(z + (size_t)b * NDIM * KDIM);
  const short* Bg = (const short*)(mu_ck + (size_t)b * CDIM * KDIM);
#pragma unroll
  for (int i = 0; i < 4; ++i) {
    int slot = i * 256 + tid;
    int r = slot >> 3, s = slot & 7, sp = s ^ (r & 7);
    g2lds16(Ag + (size_t)(n0 + r) * KDIM + sp * 8, Az + slot * 8);
  }
#pragma unroll
  for (int i = 0; i < 4; ++i) {
    int slot = i * 256 + tid;
    int r = slot >> 3, s = slot & 7, sp = s ^ (r & 7);
    g2lds16(Bg + (size_t)(c0 + r) * KDIM + sp * 8, Bm + slot * 8);
  }
  __syncthreads();
  f32x4 acc[4][4] = {};
#pragma unroll
  for (int kk = 0; kk < 2; ++kk) {
    f16x8 af[4], bf[4];
#pragma unroll
    for (int m = 0; m < 4; ++m) af[m] = ldsfrag(Az, wm * 64 + m * 16 + lr, kk, lh);
#pragma unroll
    for (int nf = 0; nf < 4; ++nf) bf[nf] = ldsfrag(Bm, wn * 64 + nf * 16 + lr, kk, lh);
#pragma unroll
    for (int m = 0; m < 4; ++m)
#pragma unroll
      for (int nf = 0; nf < 4; ++nf)
        acc[m][nf] = __builtin_amdgcn_mfma_f32_16x16x32_f16(af[m], bf[nf],
                                                            acc[m][nf], 0, 0, 0);
  }
  _Float16* ob = reconT + (size_t)b * NDIM * CDIM;
#pragma unroll
  for (int m = 0; m < 4; ++m) {
#pragma unroll
    for (int r = 0; r < 4; ++r) {
      int n = n0 + wm * 64 + m * 16 + lh * 4 + r;
#pragma unroll
      for (int nf = 0; nf < 4; ++nf) {
        int c = c0 + wn * 64 + nf * 16 + lr;
        ob[(size_t)n * CDIM + c] = (_Float16)fmaxf(acc[m][nf][r], 0.f);
      }
    }
  }
}

// ---------------------------------------------------------------------------
// final: out = relu((y-mean)*rsqrt(var+eps)*gamma + beta + x), y fp16
// ---------------------------------------------------------------------------
__global__ void k_final(float* __restrict__ out, const _Float16* __restrict__ y16,
                        const float* __restrict__ x,
                        const float* __restrict__ bnsum,
                        const float* __restrict__ bnsumsq,
                        const float* __restrict__ gamma,
                        const float* __restrict__ beta) {
  const float invM = 1.f / (BDIM * (float)NDIM);
  const size_t total4 = (size_t)BDIM * CDIM * NDIM / 4;
  for (size_t i4 = (size_t)blockIdx.x * 256 + threadIdx.x; i4 < total4;
       i4 += (size_t)gridDim.x * 256) {
    int c = (int)((i4 >> 10) & (CDIM - 1));
    float mean = bnsum[c] * invM;
    float var = bnsumsq[c] * invM - mean * mean;
    float sc = rsqrtf(var + 1e-5f) * gamma[c];
    float sh = beta[c] - mean * sc;
    f16x4 yv = *reinterpret_cast<const f16x4*>(&y16[i4 * 4]);
    float4 xv = reinterpret_cast<const float4*>(x)[i4];
    float4 o;
    o.x = fmaxf(fmaf((float)yv[0], sc, sh) + xv.x, 0.f);
    o.y = fmaxf(fmaf((float)yv[1], sc, sh) + xv.y, 0.f);
    o.z = fmaxf(fmaf((float)yv[2], sc, sh) + xv.z, 0.f);
    o.w = fmaxf(fmaf((float)yv[3], sc, sh) + xv.w, 0.f);
    reinterpret_cast<float4*>(out)[i4] = o;
  }
}

// ---------------------------------------------------------------------------
extern "C" void kernel_launch(void* const* d_in, const int* in_sizes, int n_in,
                              void* d_out, int out_size, void* d_ws,
                              size_t ws_size, hipStream_t stream) {
  const float* x = (const float*)d_in[0];
  const float* mu = (const float*)d_in[1];
  const float* w1 = (const float*)d_in[2];
  const float* b1 = (const float*)d_in[3];
  const float* w2 = (const float*)d_in[4];
  const float* gamma = (const float*)d_in[5];
  const float* beta = (const float*)d_in[6];
  float* out = (float*)d_out;

  // xf dual copies live in d_out until k_final overwrites it.
  _Float16* xfT = (_Float16*)d_out;              // [B][N][C]
  _Float16* xf = (_Float16*)d_out + 33554432;    // [B][C][N]

  _Float16* wsH = (_Float16*)d_ws;
  _Float16* xT = wsH;                            // [B][N][C] (reused as reconT)
  _Float16* reconT = wsH;
  _Float16* z = wsH + 33554432;                  // [B][N][K]
  _Float16* zT = z + 4194304;                    // [B][K][N]
  _Float16* muT = zT + 4194304;                  // [B][K][C]
  _Float16* mu_ck = muT + 524288;                // [B][C][K]
  _Float16* w1h = mu_ck + 524288;                // [C][C]
  _Float16* w2h = w1h + 262144;
  _Float16* mupart = w2h + 262144;               // [S=8][B][K][C] fp16
  float* wsF = (float*)(mupart + 4194304);
  float* colsum = wsF;                           // [B][K]   (zeroed by prep)
  float* bnsum = colsum + 1024;                  // [C]      (zeroed by prep)
  float* bnsumsq = bnsum + 512;                  // [C]      (zeroed by prep)
  _Float16* y16 = (_Float16*)(bnsumsq + 512);    // [B][C][N] fp16

  k_cvtT16<<<dim3(NDIM / 64, CDIM / 64, BDIM), 256, 0, stream>>>(x, xT);
  k_prep<<<2561, 256, 0, stream>>>(w1, w2, mu, w1h, w2h, muT, colsum);

  k_conv1_16<<<dim3(NDIM / 128, CDIM / 128, BDIM), 256, 0, stream>>>(
      xT, w1h, b1, xfT, xf);

  for (int s = 0; s < 3; ++s) {
    k_s1_16<<<dim3(NDIM / 128, BDIM), 256, 0, stream>>>(xfT, muT, z, zT, colsum,
                                                        s == 2 ? 1 : 0);
    k_s2_16<<<dim3(CDIM / 128, NSPLIT, BDIM), 256, 0, stream>>>(zT, xf, mupart);
    k_s2red<<<KDIM * BDIM, 256, 0, stream>>>(mupart, colsum, muT, mu_ck);
  }

  k_recon16<<<dim3(NDIM / 128, CDIM / 128, BDIM), 256, 0, stream>>>(z, mu_ck,
                                                                    reconT);
  k_conv2_16<<<dim3(NDIM / 128, CDIM / 128, BDIM), 256, 0, stream>>>(
      w2h, reconT, y16, bnsum, bnsumsq);

  k_final<<<4096, 256, 0, stream>>>(out, y16, x, bnsum, bnsumsq, gamma, beta);
}